// Round 9
// baseline (9058.247 us; speedup 1.0000x reference)
//
#include <hip/hip_runtime.h>
#include <math.h>

#define TT 256
#define BB 128
#define II 512
#define HH 1024
#define NCLS 1000

typedef __bf16 bf16;
typedef bf16 bf16x8 __attribute__((ext_vector_type(8)));
typedef float f32x4 __attribute__((ext_vector_type(4)));
typedef int i32x4 __attribute__((ext_vector_type(4)));

// ---------------- ws layout (bytes) ----------------
#define OFF_WHPK 0u            // 64*48*1024*2 = 6,291,456 (dead after scan; lg aliases)
#define OFF_LG   0u
#define OFF_WXPK 6291456u      // 64*64*512*2  = 4,194,304
#define OFF_BIAS 10485760u     // 16,384
#define OFF_HPK0 10502144u     // 262,144  h ping, row-major [b][1024] bf16
#define OFF_HPK1 10764288u     // 262,144  h pong
#define OFF_CBUF 11026432u     // 524,288  c state fp32 [b][1024]
#define OFF_XT   11550720u     // 33,554,432  xT[t][b][i] bf16
#define WS_BIG   45105152u

// ---------------- init: zero h0 and c ----------------
__global__ void init_state(int* __restrict__ h0i, int* __restrict__ ci) {
    int idx = blockIdx.x * 256 + threadIdx.x;
    if (idx < 65536) h0i[idx] = 0;        // 256 KB h0
    if (idx < 131072) ci[idx] = 0;        // 512 KB c
}

// ---------------- pack W_h -> WhPK[s][g*16+c][k], g in {f,i,o} ----------------
__global__ void pack_wh(const float* __restrict__ Wfh, const float* __restrict__ Wih,
                        const float* __restrict__ Woh, bf16* __restrict__ WhPK) {
    int blk = blockIdx.x;                 // 3 * 16 * 16
    int g = blk / 256, rem = blk % 256;
    int ht = rem / 16, kt = rem % 16;
    const float* src = (g == 0) ? Wfh : (g == 1) ? Wih : Woh;
    __shared__ bf16 tile[64][72];
    int tid = threadIdx.x;
    for (int i = tid; i < 4096; i += 256) {
        int kr = i >> 6, hc = i & 63;
        tile[kr][hc] = (bf16)src[(size_t)(kt * 64 + kr) * HH + ht * 64 + hc];
    }
    __syncthreads();
    for (int i = tid; i < 4096; i += 256) {
        int hc = i >> 6, kr = i & 63;
        int h = ht * 64 + hc, s = h >> 4, c = h & 15;
        WhPK[((size_t)s * 48 + g * 16 + c) * 1024 + kt * 64 + kr] = tile[kr][hc];
    }
}

// ---------------- pack W_x -> WxPK[s][g*16+c][k], g in {f,i,o,c} ----------------
__global__ void pack_wx(const float* __restrict__ Wfx, const float* __restrict__ Wix,
                        const float* __restrict__ Wox, const float* __restrict__ Wcx,
                        bf16* __restrict__ WxPK) {
    int blk = blockIdx.x;                 // 4 * 16 * 8
    int g = blk / 128, rem = blk % 128;
    int ht = rem / 8, kt = rem % 8;
    const float* src = (g == 0) ? Wfx : (g == 1) ? Wix : (g == 2) ? Wox : Wcx;
    __shared__ bf16 tile[64][72];
    int tid = threadIdx.x;
    for (int i = tid; i < 4096; i += 256) {
        int kr = i >> 6, hc = i & 63;
        tile[kr][hc] = (bf16)src[(size_t)(kt * 64 + kr) * HH + ht * 64 + hc];
    }
    __syncthreads();
    for (int i = tid; i < 4096; i += 256) {
        int hc = i >> 6, kr = i & 63;
        int h = ht * 64 + hc, s = h >> 4, c = h & 15;
        WxPK[((size_t)s * 64 + g * 16 + c) * 512 + kt * 64 + kr] = tile[kr][hc];
    }
}

__global__ void pack_bias(const float* __restrict__ bf_, const float* __restrict__ bi_,
                          const float* __restrict__ bo_, const float* __restrict__ bc_,
                          float* __restrict__ bias) {
    int i = blockIdx.x * 256 + threadIdx.x;
    if (i < 4 * HH) {
        int g = i >> 10, hn = i & 1023;
        const float* b = (g == 0) ? bf_ : (g == 1) ? bi_ : (g == 2) ? bo_ : bc_;
        bias[i] = b[hn];
    }
}

// ---------------- x[b][t][i] fp32 -> xT[t][b][i] bf16 ----------------
__global__ void conv_xT(const float* __restrict__ x, bf16* __restrict__ xT) {
    size_t o = ((size_t)blockIdx.x * 256 + threadIdx.x) * 8;
    int t = (int)(o >> 16);
    int rem = (int)(o & 65535);
    int b = rem >> 9, i = rem & 511;
    const float* s = x + ((size_t)b * TT + t) * II + i;
    float4 f0 = *(const float4*)(s);
    float4 f1 = *(const float4*)(s + 4);
    bf16x8 v;
    v[0]=(bf16)f0.x; v[1]=(bf16)f0.y; v[2]=(bf16)f0.z; v[3]=(bf16)f0.w;
    v[4]=(bf16)f1.x; v[5]=(bf16)f1.y; v[6]=(bf16)f1.z; v[7]=(bf16)f1.w;
    *(bf16x8*)(xT + o) = v;
}

__device__ __forceinline__ float sigm(float x) { return 1.0f / (1.0f + __expf(-x)); }
__device__ __forceinline__ float tanh_f(float x) {
    float e = __expf(-2.0f * fabsf(x));
    float t = (1.0f - e) / (1.0f + e);
    return copysignf(t, x);
}

// ---------------- per-timestep kernel (HW-sequenced; no software sync) ----------------
// grid 128 = 64 col-chunks x 2 row-halves; block 256 (4 waves). Wave w owns
// rows [rh*64 + w*16, +16) x cols [s*16, +16) x 4 gates. Kernel boundary
// provides the global barrier + cross-XCD coherence (round-1-proven). h A-loads
// (L3) issued first to overlap under the x-part GEMM; weights streamed from
// L3 (L2 is invalidated per dispatch); c-state in global fp32.
template<bool XB>
__global__ __launch_bounds__(256) void lstm_step(
    const float* __restrict__ xf, const bf16* __restrict__ xT,
    const bf16* __restrict__ WhPK, const bf16* __restrict__ WxPK,
    const float* __restrict__ bias, const bf16* __restrict__ hin,
    bf16* __restrict__ hout, float* __restrict__ cbuf, int t) {
    const int tid = threadIdx.x, w = tid >> 6, lane = tid & 63;
    const int s = (int)blockIdx.x >> 1, rh = (int)blockIdx.x & 1;
    const int lr = lane & 15, lkq = lane >> 4, lk = lkq * 8, rb = lkq * 4;
    const int R0 = rh * 64 + w * 16;
    const int arow = R0 + lr;             // A row this lane loads
    const int hcol = s * 16 + lr;         // D col this lane owns

    const bf16* hbase = hin + (size_t)arow * HH + lk;

    // ---- issue first half of h A-loads (L3 latency hides under x-part) ----
    i32x4 hv0[16];
    #pragma unroll
    for (int kk = 0; kk < 16; ++kk)
        hv0[kk] = *(const i32x4*)(hbase + kk * 32);

    // ---- c loads early ----
    float cold[4];
    #pragma unroll
    for (int j = 0; j < 4; ++j)
        cold[j] = cbuf[(size_t)(R0 + rb + j) * HH + hcol];

    f32x4 acc[4] = {};                    // f,i,o,c

    // ---- x-part (K=512): A from xT (or fp32 x), B = WxPK (4 gates) ----
    const bf16* wxb = WxPK + (size_t)s * 64 * 512;
    #pragma unroll 4
    for (int kk = 0; kk < 16; ++kk) {
        const int k0 = kk * 32 + lk;
        bf16x8 a;
        if (XB) {
            a = *(const bf16x8*)(xT + ((size_t)t * BB + arow) * II + k0);
        } else {
            const float* sx = xf + ((size_t)arow * TT + t) * II + k0;
            float4 f0 = *(const float4*)sx, f1 = *(const float4*)(sx + 4);
            a[0]=(bf16)f0.x; a[1]=(bf16)f0.y; a[2]=(bf16)f0.z; a[3]=(bf16)f0.w;
            a[4]=(bf16)f1.x; a[5]=(bf16)f1.y; a[6]=(bf16)f1.z; a[7]=(bf16)f1.w;
        }
        #pragma unroll
        for (int tau = 0; tau < 4; ++tau) {
            bf16x8 b = *(const bf16x8*)(wxb + (size_t)(tau * 16 + lr) * 512 + k0);
            acc[tau] = __builtin_amdgcn_mfma_f32_16x16x32_bf16(a, b, acc[tau], 0, 0, 0);
        }
    }

    // ---- issue second half of h A-loads ----
    i32x4 hv1[16];
    #pragma unroll
    for (int kk = 0; kk < 16; ++kk)
        hv1[kk] = *(const i32x4*)(hbase + (16 + kk) * 32);

    // ---- h-part (K=1024): B = WhPK (3 gates; c-gate is x-only) ----
    const bf16* whb = WhPK + (size_t)s * 48 * 1024;
    #pragma unroll 4
    for (int kk = 0; kk < 16; ++kk) {
        const int k0 = kk * 32 + lk;
        bf16x8 a = __builtin_bit_cast(bf16x8, hv0[kk]);
        #pragma unroll
        for (int tau = 0; tau < 3; ++tau) {
            bf16x8 b = *(const bf16x8*)(whb + (size_t)(tau * 16 + lr) * 1024 + k0);
            acc[tau] = __builtin_amdgcn_mfma_f32_16x16x32_bf16(a, b, acc[tau], 0, 0, 0);
        }
    }
    #pragma unroll 4
    for (int kk = 0; kk < 16; ++kk) {
        const int k0 = (16 + kk) * 32 + lk;
        bf16x8 a = __builtin_bit_cast(bf16x8, hv1[kk]);
        #pragma unroll
        for (int tau = 0; tau < 3; ++tau) {
            bf16x8 b = *(const bf16x8*)(whb + (size_t)(tau * 16 + lr) * 1024 + k0);
            acc[tau] = __builtin_amdgcn_mfma_f32_16x16x32_bf16(a, b, acc[tau], 0, 0, 0);
        }
    }

    // ---- pointwise (thread-local), plain stores (kernel boundary = fence) ----
    const float bbf = bias[0 * HH + hcol];
    const float bbi = bias[1 * HH + hcol];
    const float bbo = bias[2 * HH + hcol];
    const float bbc = bias[3 * HH + hcol];
    const int hcol0 = s * 16 + (lr & 14);
    #pragma unroll
    for (int j = 0; j < 4; ++j) {
        const int row = R0 + rb + j;
        float pf = acc[0][j] + bbf;
        float pi = acc[1][j] + bbi;
        float po = acc[2][j] + bbo;
        float pc = acc[3][j] + bbc;
        float fg = sigm(pf), ig = sigm(pi), og = sigm(po);
        float cn = tanh_f(pc) * ig + cold[j] * fg;
        cbuf[(size_t)row * HH + hcol] = cn;
        union { bf16 h; unsigned short u; } cv;
        cv.h = (bf16)(tanh_f(cn) * og);
        unsigned int mine  = (unsigned int)cv.u;
        unsigned int other = (unsigned int)__shfl_xor((int)mine, 1);
        if (!(lane & 1)) {
            unsigned int word = mine | (other << 16);
            *(unsigned int*)(hout + (size_t)row * HH + hcol0) = word;
        }
    }
}

// ---------------- head: logits = h @ W_ph + b_p ----------------
__global__ __launch_bounds__(256) void logits_kernel(
    const bf16* __restrict__ h, const float* __restrict__ Wp,
    const float* __restrict__ bp, float* __restrict__ out) {
    const int tid = threadIdx.x;
    const int r0  = blockIdx.x * 8;
    __shared__ float hs[8][HH];
    for (int i = tid; i < 8 * HH; i += 256)
        hs[i >> 10][i & 1023] = (float)h[(size_t)(r0 + (i >> 10)) * HH + (i & 1023)];
    __syncthreads();
    float acc[8][4] = {};
    for (int k = 0; k < HH; ++k) {
        float w[4];
        #pragma unroll
        for (int m = 0; m < 4; ++m) {
            int cc = tid + 256 * m;
            w[m] = (cc < NCLS) ? Wp[(size_t)k * NCLS + cc] : 0.0f;
        }
        #pragma unroll
        for (int r = 0; r < 8; ++r) {
            float hv = hs[r][k];
            #pragma unroll
            for (int m = 0; m < 4; ++m) acc[r][m] += hv * w[m];
        }
    }
    #pragma unroll
    for (int r = 0; r < 8; ++r) {
        #pragma unroll
        for (int m = 0; m < 4; ++m) {
            int cc = tid + 256 * m;
            if (cc < NCLS) out[(size_t)(r0 + r) * NCLS + cc] = acc[r][m] + bp[cc];
        }
    }
}

// ---------------- softmax over C=1000 per row ----------------
__global__ __launch_bounds__(256) void softmax_kernel(const float* __restrict__ logits,
                                                      float* __restrict__ out) {
    const int b = blockIdx.x, tid = threadIdx.x;
    __shared__ float red[256];
    float v[4];
    float mx = -1e30f;
    #pragma unroll
    for (int m = 0; m < 4; ++m) {
        int cc = tid + 256 * m;
        v[m] = (cc < NCLS) ? logits[(size_t)b * NCLS + cc] : -1e30f;
        mx = fmaxf(mx, v[m]);
    }
    red[tid] = mx; __syncthreads();
    for (int s = 128; s > 0; s >>= 1) {
        if (tid < s) red[tid] = fmaxf(red[tid], red[tid + s]);
        __syncthreads();
    }
    mx = red[0]; __syncthreads();
    float sum = 0.0f;
    #pragma unroll
    for (int m = 0; m < 4; ++m) {
        int cc = tid + 256 * m;
        if (cc < NCLS) { v[m] = __expf(v[m] - mx); sum += v[m]; }
    }
    red[tid] = sum; __syncthreads();
    for (int s = 128; s > 0; s >>= 1) {
        if (tid < s) red[tid] += red[tid + s];
        __syncthreads();
    }
    float inv = 1.0f / red[0];
    #pragma unroll
    for (int m = 0; m < 4; ++m) {
        int cc = tid + 256 * m;
        if (cc < NCLS) out[(size_t)b * NCLS + cc] = v[m] * inv;
    }
}

extern "C" void kernel_launch(void* const* d_in, const int* in_sizes, int n_in,
                              void* d_out, int out_size, void* d_ws, size_t ws_size,
                              hipStream_t stream) {
    const float* x   = (const float*)d_in[0];
    const float* Wfx = (const float*)d_in[1];
    const float* Wfh = (const float*)d_in[2];
    const float* bf_ = (const float*)d_in[3];
    const float* Wix = (const float*)d_in[4];
    const float* Wih = (const float*)d_in[5];
    const float* bi_ = (const float*)d_in[6];
    const float* Wox = (const float*)d_in[7];
    const float* Woh = (const float*)d_in[8];
    const float* bo_ = (const float*)d_in[9];
    const float* Wcx = (const float*)d_in[10];
    const float* bc_ = (const float*)d_in[11];
    const float* Wp  = (const float*)d_in[12];
    const float* bp  = (const float*)d_in[13];

    char* ws = (char*)d_ws;
    bf16*  WhPK = (bf16*)(ws + OFF_WHPK);
    bf16*  WxPK = (bf16*)(ws + OFF_WXPK);
    float* bias = (float*)(ws + OFF_BIAS);
    bf16*  hpk0 = (bf16*)(ws + OFF_HPK0);
    bf16*  hpk1 = (bf16*)(ws + OFF_HPK1);
    float* cbuf = (float*)(ws + OFF_CBUF);
    bf16*  xT   = (bf16*)(ws + OFF_XT);
    float* lg   = (float*)(ws + OFF_LG);   // aliases WhPK (dead after scan)

    init_state<<<512, 256, 0, stream>>>((int*)hpk0, (int*)cbuf);
    pack_wh<<<3 * 16 * 16, 256, 0, stream>>>(Wfh, Wih, Woh, WhPK);
    pack_wx<<<4 * 16 * 8, 256, 0, stream>>>(Wfx, Wix, Wox, Wcx, WxPK);
    pack_bias<<<16, 256, 0, stream>>>(bf_, bi_, bo_, bc_, bias);

    bf16* hping[2] = {hpk0, hpk1};
    const bool big = (ws_size >= (size_t)WS_BIG);
    if (big) {
        conv_xT<<<(BB * TT * II) / (8 * 256), 256, 0, stream>>>(x, xT);
        for (int t = 0; t < TT; ++t)
            lstm_step<true><<<128, 256, 0, stream>>>(x, xT, WhPK, WxPK, bias,
                                                     hping[t & 1], hping[(t + 1) & 1],
                                                     cbuf, t);
    } else {
        for (int t = 0; t < TT; ++t)
            lstm_step<false><<<128, 256, 0, stream>>>(x, xT, WhPK, WxPK, bias,
                                                      hping[t & 1], hping[(t + 1) & 1],
                                                      cbuf, t);
    }

    // t=255 writes hping[0] -> final h in hpk0
    logits_kernel<<<BB / 8, 256, 0, stream>>>(hpk0, Wp, bp, lg);
    softmax_kernel<<<BB, 256, 0, stream>>>(lg, (float*)d_out);
}